// Round 1
// 84.789 us; speedup vs baseline: 1.0852x; 1.0852x over previous
//
#include <hip/hip_runtime.h>
#include <hip/hip_bf16.h>
#include <math.h>

#define N 4096
#define P 128
#define H 4
#define E 32
#define NSEG 32
#define TPB 256
#define PROJ_TASKS 192

#define VSTRIDE 264          // u16 units per Vt/Ps LDS row
#define NEGF -3.0e38f

typedef __attribute__((ext_vector_type(8))) short bf16x8;
typedef __attribute__((ext_vector_type(4))) float f32x4;
typedef unsigned short u16;

__device__ __forceinline__ u16 f2b(float x) {
    __hip_bfloat16 b = __float2bfloat16(x);
    return *(u16*)&b;
}

// Split fp32 into bf16 hi (truncation) + bf16 lo (truncated residual).
// x ~= hi + lo with error ~2^-16 relative; exact residual computed in fp32.
__device__ __forceinline__ void split_tr(float v, short& hi, short& lo) {
    unsigned bits = __float_as_uint(v);
    unsigned hbits = bits & 0xFFFF0000u;
    float r = v - __uint_as_float(hbits);
    hi = (short)(bits >> 16);
    lo = (short)(__float_as_uint(r) >> 16);
}

// ---------------------------------------------------------------------------
// Counting sort (single block). 4 per-wave replicated counter banks to cut
// LDS-atomic contention 4x; shfl-scan prefix (no serial t==0 loop). Each
// wave scatters into its reserved [off + sum of earlier waves' counts) range,
// so the result is exact (intra-segment order is irrelevant to attention).
// ---------------------------------------------------------------------------
__device__ __forceinline__ void sort_phase(const int* __restrict__ pos,
                                           int* __restrict__ seg_rows,
                                           int* __restrict__ seg_off,
                                           int* sm, int t) {
    int* cnt = sm;            // [4][32]
    int* off = sm + 128;      // [33]
    int* cur = sm + 161;      // [4][32]
    const int w = t >> 6;
    if (t < 128) cnt[t] = 0;
    __syncthreads();
    for (int i = t; i < N; i += TPB) atomicAdd(&cnt[(w << 5) + pos[i]], 1);
    __syncthreads();
    if (t < 32) {
        const int c0 = cnt[t], c1 = cnt[32 + t], c2 = cnt[64 + t], c3 = cnt[96 + t];
        const int tot = c0 + c1 + c2 + c3;
        int x = tot;
#pragma unroll
        for (int d = 1; d < 32; d <<= 1) {
            int y = __shfl_up(x, d);
            if (t >= d) x += y;
        }
        const int excl = x - tot;             // exclusive prefix over segments
        off[t] = excl;
        if (t == 31) off[32] = x;
        cur[t]      = excl;
        cur[32 + t] = excl + c0;
        cur[64 + t] = excl + c0 + c1;
        cur[96 + t] = excl + c0 + c1 + c2;
    }
    __syncthreads();
    if (t <= NSEG) seg_off[t] = off[t];
    for (int i = t; i < N; i += TPB) {
        const int r = atomicAdd(&cur[(w << 5) + pos[i]], 1);
        seg_rows[r] = i;
    }
}

// ---------------------------------------------------------------------------
// One 64-row QKV projection tile via MFMA 16x16x32 bf16 with split-bf16
// error compensation (x_hi*w_hi + x_lo*w_hi + x_hi*w_lo): fp32-level
// accuracy at matrix-pipe rate. LDS-free: A rows load straight from X
// (each lane owns row m=lane&15 of its wave's 16-row strip); B fragments
// load 8 stride-512B dwords from the L2-hot W.
// MFMA layouts (m89/m91): A[m=lane&15][k=quad*8+j], B[k=quad*8+j][n=lane&15],
// C/D col=lane&15, row=quad*4+r.
// ---------------------------------------------------------------------------
__device__ __forceinline__ void proj_phase(int task,
                                           const float* __restrict__ x,
                                           const float* __restrict__ Wq, const float* __restrict__ bq,
                                           const float* __restrict__ Wk, const float* __restrict__ bk,
                                           const float* __restrict__ Wv, const float* __restrict__ bv,
                                           u16* __restrict__ Q, u16* __restrict__ Ko, u16* __restrict__ Vo,
                                           int t) {
    const int mat = task >> 6;
    const int r0  = (task & 63) * 64;
    const float* W = (mat == 0) ? Wq : (mat == 1) ? Wk : Wv;
    const float* b = (mat == 0) ? bq : (mat == 1) ? bk : bv;
    u16* y         = (mat == 0) ? Q  : (mat == 1) ? Ko : Vo;

    const int w = t >> 6, lane = t & 63, col = lane & 15, quad = lane >> 4;
    const int arow = r0 + w * 16 + col;     // this lane's A-operand row

    f32x4 acc[8];
#pragma unroll
    for (int cf = 0; cf < 8; ++cf) {
        const float bb = b[cf * 16 + col];  // D col = cf*16 + (lane&15)
        acc[cf] = (f32x4){bb, bb, bb, bb};
    }

#pragma unroll
    for (int kc = 0; kc < 4; ++kc) {
        // A fragment: 8 consecutive fp32 from this lane's row, k = kc*32+quad*8+j
        const float* xp = x + (size_t)arow * 128 + kc * 32 + quad * 8;
        const float4 a0 = *(const float4*)xp;
        const float4 a1 = *(const float4*)(xp + 4);
        const float af[8] = {a0.x, a0.y, a0.z, a0.w, a1.x, a1.y, a1.z, a1.w};
        bf16x8 ah, al;
#pragma unroll
        for (int j = 0; j < 8; ++j) {
            short h, l; split_tr(af[j], h, l);
            ah[j] = h; al[j] = l;
        }

        const float* wp = W + (size_t)(kc * 32 + quad * 8) * 128 + col;
#pragma unroll
        for (int cf = 0; cf < 8; ++cf) {
            const float* wc = wp + cf * 16;
            bf16x8 bh, bl;
#pragma unroll
            for (int j = 0; j < 8; ++j) {
                short h, l; split_tr(wc[j * 128], h, l);
                bh[j] = h; bl[j] = l;
            }
            acc[cf] = __builtin_amdgcn_mfma_f32_16x16x32_bf16(ah, bh, acc[cf], 0, 0, 0);
            acc[cf] = __builtin_amdgcn_mfma_f32_16x16x32_bf16(al, bh, acc[cf], 0, 0, 0);
            acc[cf] = __builtin_amdgcn_mfma_f32_16x16x32_bf16(ah, bl, acc[cf], 0, 0, 0);
        }
    }

#pragma unroll
    for (int cf = 0; cf < 8; ++cf) {
#pragma unroll
        for (int r = 0; r < 4; ++r) {
            y[(size_t)(r0 + w * 16 + quad * 4 + r) * 128 + cf * 16 + col] = f2b(acc[cf][r]);
        }
    }
}

// ---------------------------------------------------------------------------
// Dispatch 1: block 0 sorts; blocks 1..192 do proj tiles.
// ---------------------------------------------------------------------------
__global__ __launch_bounds__(TPB) void sort_proj_kernel(
        const float* __restrict__ inp, const int* __restrict__ pos,
        const float* __restrict__ Wq, const float* __restrict__ bq,
        const float* __restrict__ Wk, const float* __restrict__ bk,
        const float* __restrict__ Wv, const float* __restrict__ bv,
        u16* __restrict__ Q, u16* __restrict__ Kb, u16* __restrict__ Vb,
        int* __restrict__ seg_rows, int* __restrict__ seg_off) {
    __shared__ int smi[292];
    const int b = blockIdx.x;
    const int t = threadIdx.x;
    if (b == 0) {
        sort_phase(pos, seg_rows, seg_off, smi, t);
    } else {
        proj_phase(b - 1, inp, Wq, bq, Wk, bk, Wv, bv, Q, Kb, Vb, t);
    }
}

// ---------------------------------------------------------------------------
// MFMA attention body, templated on KT (number of 16-wide key tiles, 8 or
// 16). ONE tile per wave, straight-line. All trip counts compile-time.
// Layouts (mfma_f32_16x16x32_bf16, m89/m91/m120):
//   A[m=lane&15][k=quad*8+j]  B[k=quad*8+j][n=lane&15]
//   C/D: col=lane&15, row=quad*4+reg
// ---------------------------------------------------------------------------
template <int KT>
__device__ __forceinline__ void attn_body(int beg, int len, int h, int z,
                                          const u16* __restrict__ Qb,
                                          const u16* __restrict__ Kb,
                                          const u16* __restrict__ Vb,
                                          const int* __restrict__ seg_rows,
                                          float* __restrict__ out,
                                          u16* __restrict__ smu,
                                          int t, int w, int col, int quad) {
    const float scale = 0.17677669529663687f;   // 1/sqrt(32)
    u16* Vt = smu;
    u16* Ps = smu + (32 + w * 16) * VSTRIDE;

    // ---- stage KT*16 keys of V transposed (vector loads, zero-padded) ----
#pragma unroll
    for (int ii = 0; ii < KT / 4; ++ii) {            // KT*64 slots / 256 threads
        const int idx = ii * TPB + t;
        const int key = idx >> 2, c = idx & 3;
        bf16x8 v = {0, 0, 0, 0, 0, 0, 0, 0};
        if (key < len)
            v = *(const bf16x8*)(Vb + (size_t)seg_rows[beg + key] * 128 + h * 32 + c * 8);
#pragma unroll
        for (int j = 0; j < 8; ++j)
            Vt[(c * 8 + j) * VSTRIDE + key] = (u16)v[j];
    }
    // no barrier yet — QK/softmax doesn't touch Vt

    const int tt = z * 4 + w;            // ONE 16-query tile per wave
    const bool have = (tt * 16 < len);
    float lrow[4];

    if (have) {
        const int qi = beg + min(tt * 16 + col, len - 1);
        const bf16x8 qa = *(const bf16x8*)(Qb + (size_t)seg_rows[qi] * 128 + h * 32 + quad * 8);

        int krow[KT];
#pragma unroll
        for (int kt = 0; kt < KT; ++kt)
            krow[kt] = seg_rows[beg + min(kt * 16 + col, len - 1)];

        f32x4 S[KT];
#pragma unroll
        for (int kt = 0; kt < KT; ++kt) {
            const bf16x8 kb = *(const bf16x8*)(Kb + (size_t)krow[kt] * 128 + h * 32 + quad * 8);
            f32x4 c = {0.f, 0.f, 0.f, 0.f};
            S[kt] = __builtin_amdgcn_mfma_f32_16x16x32_bf16(qa, kb, c, 0, 0, 0);
        }

        float mrow[4] = {NEGF, NEGF, NEGF, NEGF};
#pragma unroll
        for (int kt = 0; kt < KT; ++kt) {
            const bool kvalid = (kt * 16 + col) < len;
#pragma unroll
            for (int r = 0; r < 4; ++r) {
                const float sc = kvalid ? S[kt][r] * scale : NEGF;
                S[kt][r] = sc;
                mrow[r] = fmaxf(mrow[r], sc);
            }
        }
#pragma unroll
        for (int d = 1; d < 16; d <<= 1) {
#pragma unroll
            for (int r = 0; r < 4; ++r)
                mrow[r] = fmaxf(mrow[r], __shfl_xor(mrow[r], d));
        }
        lrow[0] = lrow[1] = lrow[2] = lrow[3] = 0.f;
#pragma unroll
        for (int kt = 0; kt < KT; ++kt) {
#pragma unroll
            for (int r = 0; r < 4; ++r) {
                const float p = __expf(S[kt][r] - mrow[r]);   // masked -> 0
                S[kt][r] = p;
                lrow[r] += p;
            }
        }
#pragma unroll
        for (int d = 1; d < 16; d <<= 1) {
#pragma unroll
            for (int r = 0; r < 4; ++r)
                lrow[r] += __shfl_xor(lrow[r], d);
        }
#pragma unroll
        for (int kt = 0; kt < KT; ++kt) {
#pragma unroll
            for (int r = 0; r < 4; ++r)
                Ps[(quad * 4 + r) * VSTRIDE + kt * 16 + col] = f2b(S[kt][r]);
        }
    }

    __syncthreads();   // Vt ready; block-uniform path, every thread executes

    if (have) {
        f32x4 o0 = {0.f, 0.f, 0.f, 0.f}, o1 = {0.f, 0.f, 0.f, 0.f};
#pragma unroll
        for (int kg = 0; kg < KT / 2; ++kg) {
            const bf16x8 pa = *(const bf16x8*)(Ps + col * VSTRIDE + kg * 32 + quad * 8);
            const bf16x8 v0 = *(const bf16x8*)(Vt + col * VSTRIDE + kg * 32 + quad * 8);
            const bf16x8 v1 = *(const bf16x8*)(Vt + (16 + col) * VSTRIDE + kg * 32 + quad * 8);
            o0 = __builtin_amdgcn_mfma_f32_16x16x32_bf16(pa, v0, o0, 0, 0, 0);
            o1 = __builtin_amdgcn_mfma_f32_16x16x32_bf16(pa, v1, o1, 0, 0, 0);
        }
#pragma unroll
        for (int r = 0; r < 4; ++r) {
            const int qloc = tt * 16 + quad * 4 + r;
            if (qloc < len) {
                const int orow = seg_rows[beg + qloc];
                const float inv = 1.0f / lrow[r];
                float* op = out + (size_t)orow * 128 + h * 32;
                op[col]      = o0[r] * inv;
                op[16 + col] = o1[r] * inv;
            }
        }
    }
}

// ---------------------------------------------------------------------------
// Dispatch 2: MFMA attention. Grid (NSEG, H, 4), block 256 = 4 waves, one
// 16-query tile per wave. Block-uniform KT=8 fast path for len<=128.
// ---------------------------------------------------------------------------
__global__ __launch_bounds__(TPB) void attn_kernel(const u16* __restrict__ Qb,
                                                   const u16* __restrict__ Kb,
                                                   const u16* __restrict__ Vb,
                                                   const int* __restrict__ seg_rows,
                                                   const int* __restrict__ seg_off,
                                                   float* __restrict__ out) {
    __shared__ u16 smu[VSTRIDE * (32 + 4 * 16)];   // Vt(32 rows) + 4x Ps(16 rows)

    const int s = blockIdx.x, h = blockIdx.y, z = blockIdx.z;
    const int beg = seg_off[s];
    const int len = seg_off[s + 1] - beg;
    if (z * 64 >= len) return;                     // dead query range
    const int t = threadIdx.x, w = t >> 6;
    const int lane = t & 63, col = lane & 15, quad = lane >> 4;

    if (len <= 128)
        attn_body<8>(beg, len, h, z, Qb, Kb, Vb, seg_rows, out, smu, t, w, col, quad);
    else
        attn_body<16>(beg, len, h, z, Qb, Kb, Vb, seg_rows, out, smu, t, w, col, quad);
}

// ---------------------------------------------------------------------------
extern "C" void kernel_launch(void* const* d_in, const int* in_sizes, int n_in,
                              void* d_out, int out_size, void* d_ws, size_t ws_size,
                              hipStream_t stream) {
    const float* inp = (const float*)d_in[0];
    const int*   pos = (const int*)d_in[1];
    const float* Wq  = (const float*)d_in[2];
    const float* bq  = (const float*)d_in[3];
    const float* Wk  = (const float*)d_in[4];
    const float* bk  = (const float*)d_in[5];
    const float* Wv  = (const float*)d_in[6];
    const float* bv  = (const float*)d_in[7];
    float* out = (float*)d_out;

    u16* Qb = (u16*)d_ws;
    u16* Kb = Qb + (size_t)N * 128;
    u16* Vb = Kb + (size_t)N * 128;
    int* seg_rows = (int*)(Vb + (size_t)N * 128);
    int* seg_off  = seg_rows + N;          // NSEG+1

    sort_proj_kernel<<<1 + PROJ_TASKS, TPB, 0, stream>>>(
        inp, pos, Wq, bq, Wk, bk, Wv, bv, Qb, Kb, Vb, seg_rows, seg_off);

    attn_kernel<<<dim3(NSEG, H, 4), TPB, 0, stream>>>(
        Qb, Kb, Vb, seg_rows, seg_off, out);
}